// Round 8
// baseline (899.925 us; speedup 1.0000x reference)
//
#include <hip/hip_runtime.h>
#include <hip/hip_bf16.h>
#include <math.h>

// GAT, 4 layers: N=50000, E=800000, IN=128, HID=64, H=4, C=2.
// R13 481.9 -> R15 474.6 -> R17 449.6. agg64 x3=205us CLOSED.
// R18 FAILED (772.7): single-line barrier -> 512 spinners @0.21us flooded one
// L3 line (~2400 polls/us vs ~600/us service) -> RMW starvation, 90us/barrier.
// Clean attribution: R17's 5-dispatch CSR chain = 67us; real work ~28us.
// R19: de-contended barrier: 8 striped arrive counters (64 RMW/line), block-0
// detect, 8 replicated release flags, s_sleep(32) polls (~75/us/line, 12% of
// line service). Fallback if csr_k > 70us: revert to R17 dispatches.
// R20: identical resubmit — R19 bench was an infra failure (3rd occurrence of
// this signature; R13/R16 resubmits passed). Deadlock audit clean: 4 uncond
// barriers, monotone counter, 12 VGPR/512B LDS -> all 512 blocks co-resident,
// memset replayed per-launch (R18 profile showed ~30 clean iterations).

#define LEAKY_SLOPE 0.2f

typedef __bf16 bf16x8_t __attribute__((ext_vector_type(8)));
typedef float f32x4_t __attribute__((ext_vector_type(4)));
typedef float f32x2_t __attribute__((ext_vector_type(2)));

__device__ __forceinline__ float leaky(float x) { return x > 0.f ? x : LEAKY_SLOPE * x; }
__device__ __forceinline__ float eluf(float x)  { return x > 0.f ? x : expm1f(x); }
__device__ __forceinline__ float bflo(unsigned u) { return __uint_as_float(u << 16); }
__device__ __forceinline__ float bfhi(unsigned u) { return __uint_as_float(u & 0xffff0000u); }
__device__ __forceinline__ unsigned pk2(float a, float b) {
  __hip_bfloat162 t;
  t.x = __float2bfloat16(a);
  t.y = __float2bfloat16(b);
  return *(unsigned*)&t;
}

__device__ __forceinline__ float rlf(float v, int l) {
  return __uint_as_float((unsigned)__builtin_amdgcn_readlane((int)__float_as_uint(v), l));
}
template <int CTRL>
__device__ __forceinline__ float dpp_add(float x) {
  int t = __builtin_amdgcn_update_dpp(0, (int)__float_as_uint(x), CTRL, 0xf, 0xf, false);
  return x + __uint_as_float((unsigned)t);
}
__device__ __forceinline__ float wsum_dpp(float x) {
  x = dpp_add<0x111>(x);
  x = dpp_add<0x112>(x);
  x = dpp_add<0x114>(x);
  x = dpp_add<0x118>(x);
  x = dpp_add<0x142>(x);
  x = dpp_add<0x143>(x);
  return rlf(x, 63);
}
__device__ __forceinline__ float rowsum_dpp(float x) {
  x = dpp_add<0x111>(x);
  x = dpp_add<0x112>(x);
  x = dpp_add<0x114>(x);
  x = dpp_add<0x118>(x);
  return x;
}
__device__ __forceinline__ float wmax(float v) {
#pragma unroll
  for (int o = 32; o; o >>= 1) v = fmaxf(v, __shfl_xor(v, o));
  return v;
}
__device__ __forceinline__ float wsum_sh(float v) {
#pragma unroll
  for (int o = 32; o; o >>= 1) v += __shfl_xor(v, o);
  return v;
}

// 8-col fma: u = 8 consecutive bf16 of one head, scalar weight w
__device__ __forceinline__ void quad_fma(f32x2_t& a0, f32x2_t& a1, f32x2_t& a2, f32x2_t& a3,
                                         uint4 u, float w) {
  f32x2_t wv = {w, w};
  f32x2_t f;
  f[0] = bflo(u.x); f[1] = bfhi(u.x); a0 = __builtin_elementwise_fma(wv, f, a0);
  f[0] = bflo(u.y); f[1] = bfhi(u.y); a1 = __builtin_elementwise_fma(wv, f, a1);
  f[0] = bflo(u.z); f[1] = bfhi(u.z); a2 = __builtin_elementwise_fma(wv, f, a2);
  f[0] = bflo(u.w); f[1] = bfhi(u.w); a3 = __builtin_elementwise_fma(wv, f, a3);
}

// async global->LDS, 16B per lane
__device__ __forceinline__ void gl_lds16(const __hip_bfloat16* g, __bf16* l) {
  __builtin_amdgcn_global_load_lds((const __attribute__((address_space(1))) void*)g,
                                   (__attribute__((address_space(3))) void*)l, 16, 0, 0);
}

// ---------------- de-contended device barrier ----------------
// cnt: 8 striped arrive counters (64B apart); rel: 8 replicated release flags.
// Monotone, never reset; zeroed by 1KB memset pre-launch. All blocks arrive
// unconditionally; block 0 detects and releases.
__device__ __forceinline__ void gsync(int* cnt, int* rel, int phase, int nblk) {
  __syncthreads();
  __threadfence();
  const int bid = blockIdx.x;
  if (threadIdx.x == 0) {
    __hip_atomic_fetch_add(&cnt[(bid & 7) << 4], 1, __ATOMIC_RELAXED,
                           __HIP_MEMORY_SCOPE_AGENT);
    if (bid == 0) {
      const int target = nblk * (phase + 1);
      for (;;) {
        int s = 0;
#pragma unroll
        for (int i = 0; i < 8; ++i)
          s += __hip_atomic_load(&cnt[i << 4], __ATOMIC_RELAXED, __HIP_MEMORY_SCOPE_AGENT);
        if (s >= target) break;
        __builtin_amdgcn_s_sleep(16);
      }
      __threadfence();
#pragma unroll
      for (int i = 0; i < 8; ++i)
        __hip_atomic_store(&rel[i << 4], phase + 1, __ATOMIC_RELEASE,
                           __HIP_MEMORY_SCOPE_AGENT);
    } else {
      while (__hip_atomic_load(&rel[(bid & 7) << 4], __ATOMIC_ACQUIRE,
                               __HIP_MEMORY_SCOPE_AGENT) < phase + 1)
        __builtin_amdgcn_s_sleep(32);
    }
  }
  __syncthreads();
  __threadfence();
}

__global__ __launch_bounds__(256) void csr_k(
    const float* __restrict__ W1, const float* __restrict__ W2,
    const float* __restrict__ W3, const float* __restrict__ W4,
    const float* __restrict__ rW4,
    __hip_bfloat16* __restrict__ W1b, __hip_bfloat16* __restrict__ W2b,
    __hip_bfloat16* __restrict__ W3b, __hip_bfloat16* __restrict__ Wcatb,
    const int* __restrict__ src, const int* __restrict__ dst,
    int* __restrict__ deg, int* __restrict__ slot,
    int* __restrict__ rowp, int* __restrict__ rowpf,
    int* __restrict__ bsum, int* __restrict__ bpre,
    int* __restrict__ csrc, int* __restrict__ cnt, int* __restrict__ rel,
    int n, int e) {
  const int tid = threadIdx.x, bid = blockIdx.x;
  const int gsz = gridDim.x * 256;
  const int gi = bid * 256 + tid;
  const int nblk = gridDim.x;
  const int nch = (n + 1023) >> 10;  // 49

  // ---- phase 0: zero deg + weight cvt ----
  for (int i = gi; i < n; i += gsz) deg[i] = 0;
  for (int i = gi; i < 41984; i += gsz) {
    const float* sp;
    __hip_bfloat16* dp;
    int idx;
    if (i < 8192)       { sp = W1;  dp = W1b;          idx = i; }
    else if (i < 24576) { sp = W2;  dp = W2b;          idx = i - 8192; }
    else if (i < 40960) { sp = W3;  dp = W3b;          idx = i - 24576; }
    else if (i < 41472) { sp = W4;  dp = Wcatb;        idx = i - 40960; }
    else                { sp = rW4; dp = Wcatb + 2048; idx = i - 41472; }
    float4 wv = ((const float4*)sp)[idx];
    uint2 o = {pk2(wv.x, wv.y), pk2(wv.z, wv.w)};
    ((uint2*)dp)[idx] = o;
  }
  gsync(cnt, rel, 0, nblk);

  // ---- phase 1: histogram with slot capture ----
  for (int i = gi; i < e; i += gsz) slot[i] = atomicAdd(&deg[dst[i]], 1);
  gsync(cnt, rel, 1, nblk);

  // ---- phase 2a: per-1024-chunk exclusive scans (blocks 0..nch-1) ----
  __shared__ int wtot[4], wpre[4];
  if (bid < nch) {
    int base = bid << 10;
    int idx = base + tid * 4;
    int d0 = 0, d1 = 0, d2 = 0, d3 = 0;
    if (idx + 3 < n) {
      int4 q = *(const int4*)(deg + idx);
      d0 = q.x; d1 = q.y; d2 = q.z; d3 = q.w;
    } else {
      if (idx < n)     d0 = deg[idx];
      if (idx + 1 < n) d1 = deg[idx + 1];
      if (idx + 2 < n) d2 = deg[idx + 2];
      if (idx + 3 < n) d3 = deg[idx + 3];
    }
    int t = d0 + d1 + d2 + d3;
    int lane = tid & 63, wv2 = tid >> 6;
    int X = t;
#pragma unroll
    for (int off = 1; off < 64; off <<= 1) {
      int u = __shfl_up(X, off);
      if (lane >= off) X += u;
    }
    if (lane == 63) wtot[wv2] = X;
    __syncthreads();
    if (tid < 4) {
      int s4 = wtot[tid];
      int y = s4;
#pragma unroll
      for (int off = 1; off < 4; off <<= 1) {
        int u = __shfl_up(y, off);
        if (tid >= off) y += u;
      }
      wpre[tid] = y - s4;
      if (tid == 3) bsum[bid] = y;
    }
    __syncthreads();
    int ex = wpre[wv2] + X - t;
    if (idx < n)     rowp[idx]     = ex;
    if (idx + 1 < n) rowp[idx + 1] = ex + d0;
    if (idx + 2 < n) rowp[idx + 2] = ex + d0 + d1;
    if (idx + 3 < n) rowp[idx + 3] = ex + d0 + d1 + d2;
  }
  gsync(cnt, rel, 2, nblk);

  // ---- phase 2b: scan chunk totals (block 0, one wave) ----
  if (bid == 0 && tid < 64) {
    int v = (tid < nch) ? bsum[tid] : 0;
    int x = v;
#pragma unroll
    for (int off = 1; off < 64; off <<= 1) {
      int u = __shfl_up(x, off);
      if (tid >= off) x += u;
    }
    if (tid < nch) bpre[tid] = x - v;
    if (tid == nch - 1) bpre[nch] = x;
  }
  gsync(cnt, rel, 3, nblk);

  // ---- phase 3: scatter + finalize rowp ----
  for (int i = gi; i < e; i += gsz) {
    int d = dst[i];
    csrc[rowp[d] + bpre[d >> 10] + slot[i]] = src[i];
  }
  for (int i = gi; i <= n; i += gsz)
    rowpf[i] = (i == n) ? bpre[nch] : rowp[i] + bpre[i >> 10];
}

// ---------------- layer-1 GEMM: f32 A read directly, reg-stage cvt ----------------
__global__ __launch_bounds__(256) void gemm1f_mfma(const float* __restrict__ A,
                                                   const __hip_bfloat16* __restrict__ B,
                                                   __hip_bfloat16* __restrict__ featb,
                                                   const float* __restrict__ al,
                                                   const float* __restrict__ ar,
                                                   float* __restrict__ el,
                                                   float* __restrict__ er, int n, int nbx) {
  __shared__ __bf16 As[2][128 * 32];
  __shared__ __bf16 Bs[2][128 * 32];
  const int wg = blockIdx.x;
  const int b = ((wg >> 4) << 3) + (wg & 7);
  if (b >= nbx) return;
  const int cb = (wg >> 3) & 1;
  const int r0 = b * 128, c0 = cb * 128;

  const int tid = threadIdx.x;
  const int lane = tid & 63, w = tid >> 6;
  const int tm = lane & 15, tq = lane >> 4;
  const int wm = (w & 1) * 64, wn = (w >> 1) * 64;

  f32x4_t acc[4][4];
#pragma unroll
  for (int i = 0; i < 4; ++i)
#pragma unroll
    for (int j = 0; j < 4; ++j) acc[i][j] = 0.f;

  const int srow = tid >> 1;
  const int sh = tid & 1;
  const int arw = r0 + srow;
  const bool aok = arw < n;
  const float* ap = A + (size_t)arw * 128 + sh * 32;

  const int srB = w * 32 + (lane >> 2);
  const int scB = (lane & 3) * 8;
  const __hip_bfloat16* gb0 = B + (size_t)(c0 + srB) * 128 + scB;

#pragma unroll
  for (int kk = 0; kk < 128; kk += 64) {
    float4 av0 = {0, 0, 0, 0}, av1 = {0, 0, 0, 0}, av2 = {0, 0, 0, 0}, av3 = {0, 0, 0, 0};
    float4 av4 = {0, 0, 0, 0}, av5 = {0, 0, 0, 0}, av6 = {0, 0, 0, 0}, av7 = {0, 0, 0, 0};
    if (aok) {
      const float4* p = (const float4*)(ap + kk);
      av0 = p[0]; av1 = p[1]; av2 = p[2]; av3 = p[3];
      av4 = p[4]; av5 = p[5]; av6 = p[6]; av7 = p[7];
    }
    __syncthreads();
    const __hip_bfloat16* gbk = gb0 + kk;
    gl_lds16(gbk, &Bs[0][w * 1024]);
    gl_lds16(gbk + (size_t)16 * 128, &Bs[0][w * 1024 + 512]);
    gl_lds16(gbk + 32, &Bs[1][w * 1024]);
    gl_lds16(gbk + (size_t)16 * 128 + 32, &Bs[1][w * 1024 + 512]);
    {
      uint4 o;
      o.x = pk2(av0.x, av0.y); o.y = pk2(av0.z, av0.w);
      o.z = pk2(av1.x, av1.y); o.w = pk2(av1.z, av1.w);
      *(uint4*)&As[sh][srow * 32 + 0] = o;
      o.x = pk2(av2.x, av2.y); o.y = pk2(av2.z, av2.w);
      o.z = pk2(av3.x, av3.y); o.w = pk2(av3.z, av3.w);
      *(uint4*)&As[sh][srow * 32 + 8] = o;
      o.x = pk2(av4.x, av4.y); o.y = pk2(av4.z, av4.w);
      o.z = pk2(av5.x, av5.y); o.w = pk2(av5.z, av5.w);
      *(uint4*)&As[sh][srow * 32 + 16] = o;
      o.x = pk2(av6.x, av6.y); o.y = pk2(av6.z, av6.w);
      o.z = pk2(av7.x, av7.y); o.w = pk2(av7.z, av7.w);
      *(uint4*)&As[sh][srow * 32 + 24] = o;
    }
    __syncthreads();
#pragma unroll
    for (int ks = 0; ks < 2; ++ks) {
      bf16x8_t af[4], bfr[4];
#pragma unroll
      for (int i = 0; i < 4; ++i)
        af[i] = *(const bf16x8_t*)&As[ks][(wm + i * 16 + tm) * 32 + tq * 8];
#pragma unroll
      for (int j = 0; j < 4; ++j)
        bfr[j] = *(const bf16x8_t*)&Bs[ks][(wn + j * 16 + tm) * 32 + tq * 8];
#pragma unroll
      for (int i = 0; i < 4; ++i)
#pragma unroll
        for (int j = 0; j < 4; ++j)
          acc[i][j] = __builtin_amdgcn_mfma_f32_16x16x32_bf16(af[i], bfr[j], acc[i][j], 0, 0, 0);
    }
  }

  // featb store, row-major
#pragma unroll
  for (int i = 0; i < 4; ++i) {
#pragma unroll
    for (int j = 0; j < 4; ++j) {
      int col = c0 + wn + j * 16 + tm;
#pragma unroll
      for (int rr = 0; rr < 4; ++rr) {
        int row = r0 + wm + i * 16 + tq * 4 + rr;
        if (row < n) featb[(size_t)row * 256 + col] = __float2bfloat16(acc[i][j][rr]);
      }
    }
  }

  // el/er epilogue
  {
    const int hd = (c0 + wn) >> 6;
    float alv[4], arv[4];
#pragma unroll
    for (int j = 0; j < 4; ++j) {
      alv[j] = al[hd * 64 + j * 16 + tm];
      arv[j] = ar[hd * 64 + j * 16 + tm];
    }
#pragma unroll
    for (int i = 0; i < 4; ++i) {
#pragma unroll
      for (int rr = 0; rr < 4; ++rr) {
        float se = acc[i][0][rr] * alv[0] + acc[i][1][rr] * alv[1] +
                   acc[i][2][rr] * alv[2] + acc[i][3][rr] * alv[3];
        float sr2 = acc[i][0][rr] * arv[0] + acc[i][1][rr] * arv[1] +
                    acc[i][2][rr] * arv[2] + acc[i][3][rr] * arv[3];
        se = rowsum_dpp(se);
        sr2 = rowsum_dpp(sr2);
        if (tm == 15) {
          int row = r0 + wm + i * 16 + tq * 4 + rr;
          if (row < n) {
            el[(size_t)row * 4 + hd] = se;
            er[(size_t)row * 4 + hd] = sr2;
          }
        }
      }
    }
  }
}

// ---------------- MFMA GEMM (bf16 A), layers 2-3 ----------------
template <int K>
__global__ __launch_bounds__(256) void gemm_mfma(const __hip_bfloat16* __restrict__ A,
                                                 const __hip_bfloat16* __restrict__ B,
                                                 __hip_bfloat16* __restrict__ featb,
                                                 const float* __restrict__ al,
                                                 const float* __restrict__ ar,
                                                 float* __restrict__ el,
                                                 float* __restrict__ er, int n, int nbx) {
  __shared__ __bf16 As[2][128 * 32];
  __shared__ __bf16 Bs[2][128 * 32];
  const int wg = blockIdx.x;
  const int b = ((wg >> 4) << 3) + (wg & 7);
  if (b >= nbx) return;
  const int cb = (wg >> 3) & 1;
  const int r0 = b * 128, c0 = cb * 128;

  const int tid = threadIdx.x;
  const int lane = tid & 63, w = tid >> 6;
  const int tm = lane & 15, tq = lane >> 4;
  const int wm = (w & 1) * 64, wn = (w >> 1) * 64;

  f32x4_t acc[4][4];
#pragma unroll
  for (int i = 0; i < 4; ++i)
#pragma unroll
    for (int j = 0; j < 4; ++j) acc[i][j] = 0.f;

  const bool interior = (r0 + 128 <= n);
  if (interior) {
    const int srow = w * 32 + (lane >> 2);
    const int scol = (lane & 3) * 8;
    const __hip_bfloat16* ga0 = A + (size_t)(r0 + srow) * K + scol;
    const __hip_bfloat16* gb0 = B + (size_t)(c0 + srow) * K + scol;
    for (int kk = 0; kk < K; kk += 64) {
      const __hip_bfloat16* ga = ga0 + kk;
      const __hip_bfloat16* gb = gb0 + kk;
      __syncthreads();
      gl_lds16(ga, &As[0][w * 1024]);
      gl_lds16(ga + (size_t)16 * K, &As[0][w * 1024 + 512]);
      gl_lds16(ga + 32, &As[1][w * 1024]);
      gl_lds16(ga + (size_t)16 * K + 32, &As[1][w * 1024 + 512]);
      gl_lds16(gb, &Bs[0][w * 1024]);
      gl_lds16(gb + (size_t)16 * K, &Bs[0][w * 1024 + 512]);
      gl_lds16(gb + 32, &Bs[1][w * 1024]);
      gl_lds16(gb + (size_t)16 * K + 32, &Bs[1][w * 1024 + 512]);
      __syncthreads();
#pragma unroll
      for (int ks = 0; ks < 2; ++ks) {
        bf16x8_t af[4], bfr[4];
#pragma unroll
        for (int i = 0; i < 4; ++i)
          af[i] = *(const bf16x8_t*)&As[ks][(wm + i * 16 + tm) * 32 + tq * 8];
#pragma unroll
        for (int j = 0; j < 4; ++j)
          bfr[j] = *(const bf16x8_t*)&Bs[ks][(wn + j * 16 + tm) * 32 + tq * 8];
#pragma unroll
        for (int i = 0; i < 4; ++i)
#pragma unroll
          for (int j = 0; j < 4; ++j)
            acc[i][j] = __builtin_amdgcn_mfma_f32_16x16x32_bf16(af[i], bfr[j], acc[i][j], 0, 0, 0);
      }
    }
  } else {
    const int srow = tid >> 1, sko = (tid & 1) * 16;
    for (int kk = 0; kk < K; kk += 32) {
      uint4 av0 = {0, 0, 0, 0}, av1 = {0, 0, 0, 0};
      int arw = r0 + srow;
      if (arw < n) {
        const uint4* p = (const uint4*)(A + (size_t)arw * K + kk + sko);
        av0 = p[0];
        av1 = p[1];
      }
      const uint4* q = (const uint4*)(B + (size_t)(c0 + srow) * K + kk + sko);
      uint4 bv0 = q[0], bv1 = q[1];
      __syncthreads();
      *(uint4*)&As[0][srow * 32 + sko] = av0;
      *(uint4*)&As[0][srow * 32 + sko + 8] = av1;
      *(uint4*)&Bs[0][srow * 32 + sko] = bv0;
      *(uint4*)&Bs[0][srow * 32 + sko + 8] = bv1;
      __syncthreads();
      bf16x8_t af[4], bfr[4];
#pragma unroll
      for (int i = 0; i < 4; ++i)
        af[i] = *(const bf16x8_t*)&As[0][(wm + i * 16 + tm) * 32 + tq * 8];
#pragma unroll
      for (int j = 0; j < 4; ++j)
        bfr[j] = *(const bf16x8_t*)&Bs[0][(wn + j * 16 + tm) * 32 + tq * 8];
#pragma unroll
      for (int i = 0; i < 4; ++i)
#pragma unroll
        for (int j = 0; j < 4; ++j)
          acc[i][j] = __builtin_amdgcn_mfma_f32_16x16x32_bf16(af[i], bfr[j], acc[i][j], 0, 0, 0);
    }
  }

  // featb store, row-major
#pragma unroll
  for (int i = 0; i < 4; ++i) {
#pragma unroll
    for (int j = 0; j < 4; ++j) {
      int col = c0 + wn + j * 16 + tm;
#pragma unroll
      for (int rr = 0; rr < 4; ++rr) {
        int row = r0 + wm + i * 16 + tq * 4 + rr;
        if (row < n) featb[(size_t)row * 256 + col] = __float2bfloat16(acc[i][j][rr]);
      }
    }
  }

  // el/er epilogue
  {
    const int hd = (c0 + wn) >> 6;
    float alv[4], arv[4];
#pragma unroll
    for (int j = 0; j < 4; ++j) {
      alv[j] = al[hd * 64 + j * 16 + tm];
      arv[j] = ar[hd * 64 + j * 16 + tm];
    }
#pragma unroll
    for (int i = 0; i < 4; ++i) {
#pragma unroll
      for (int rr = 0; rr < 4; ++rr) {
        float se = acc[i][0][rr] * alv[0] + acc[i][1][rr] * alv[1] +
                   acc[i][2][rr] * alv[2] + acc[i][3][rr] * alv[3];
        float sr2 = acc[i][0][rr] * arv[0] + acc[i][1][rr] * arv[1] +
                    acc[i][2][rr] * arv[2] + acc[i][3][rr] * arv[3];
        se = rowsum_dpp(se);
        sr2 = rowsum_dpp(sr2);
        if (tm == 15) {
          int row = r0 + wm + i * 16 + tq * 4 + rr;
          if (row < n) {
            el[(size_t)row * 4 + hd] = se;
            er[(size_t)row * 4 + hd] = sr2;
          }
        }
      }
    }
  }
}

// ---------------- aggregate layers 1-3 (at random-gather service wall) ----------------
template <int RES>
__global__ __launch_bounds__(256) void agg64_k(const __hip_bfloat16* __restrict__ featb,
                                               const float* __restrict__ el,
                                               const float* __restrict__ er,
                                               const int* __restrict__ rowp,
                                               const int* __restrict__ csrc,
                                               const __hip_bfloat16* __restrict__ hinb,
                                               const float* __restrict__ bias,
                                               __hip_bfloat16* __restrict__ houtb, int n) {
  __shared__ float wsh[4][256];
  __shared__ int ssh[4][64];
  int wv = threadIdx.x >> 6;
  int node = blockIdx.x * 4 + wv;
  int lane = threadIdx.x & 63;
  if (node >= n) return;
  int s0 = rowp[node], s1 = rowp[node + 1];
  int deg = s1 - s0;
  float4 erv = *(const float4*)(er + (size_t)node * 4);

  if (deg <= 64) {
    int sown = 0;
    float x0 = 0.f, x1 = 0.f, x2 = 0.f, x3 = 0.f;
    if (lane < deg) {
      sown = csrc[s0 + lane];
      float4 e = *(const float4*)(el + (size_t)sown * 4);
      x0 = __expf(leaky(e.x + erv.x));
      x1 = __expf(leaky(e.y + erv.y));
      x2 = __expf(leaky(e.z + erv.z));
      x3 = __expf(leaky(e.w + erv.w));
    }
    float d0 = wsum_dpp(x0), d1 = wsum_dpp(x1), d2 = wsum_dpp(x2), d3 = wsum_dpp(x3);
    float i0 = d0 > 0.f ? 1.f / d0 : 0.f;
    float i1 = d1 > 0.f ? 1.f / d1 : 0.f;
    float i2 = d2 > 0.f ? 1.f / d2 : 0.f;
    float i3 = d3 > 0.f ? 1.f / d3 : 0.f;
    float4 wq = {x0 * i0, x1 * i1, x2 * i2, x3 * i3};
    *(float4*)&wsh[wv][lane * 4] = wq;
    ssh[wv][lane] = sown;

    const int half = lane >> 5, sub = lane & 31;
    const int hh = sub >> 3;
    f32x2_t a0 = {0.f, 0.f}, a1 = {0.f, 0.f}, a2 = {0.f, 0.f}, a3 = {0.f, 0.f};
    const int G = deg >> 3;
    int k = 0;
    if (G) {
      int ke = half;
      int sk0 = ssh[wv][ke], sk1 = ssh[wv][ke + 2];
      int sk2 = ssh[wv][ke + 4], sk3 = ssh[wv][ke + 6];
      uint4 u0 = ((const uint4*)(featb + ((size_t)sk0 << 8)))[sub];
      uint4 u1 = ((const uint4*)(featb + ((size_t)sk1 << 8)))[sub];
      uint4 u2 = ((const uint4*)(featb + ((size_t)sk2 << 8)))[sub];
      uint4 u3 = ((const uint4*)(featb + ((size_t)sk3 << 8)))[sub];
      float w0 = wsh[wv][ke * 4 + hh];
      float w1 = wsh[wv][(ke + 2) * 4 + hh];
      float w2 = wsh[wv][(ke + 4) * 4 + hh];
      float w3 = wsh[wv][(ke + 6) * 4 + hh];
      for (int g = 1; g < G; ++g) {
        int kb = g * 8 + half;
        int t0 = ssh[wv][kb], t1 = ssh[wv][kb + 2];
        int t2 = ssh[wv][kb + 4], t3 = ssh[wv][kb + 6];
        uint4 v0 = ((const uint4*)(featb + ((size_t)t0 << 8)))[sub];
        uint4 v1 = ((const uint4*)(featb + ((size_t)t1 << 8)))[sub];
        uint4 v2 = ((const uint4*)(featb + ((size_t)t2 << 8)))[sub];
        uint4 v3 = ((const uint4*)(featb + ((size_t)t3 << 8)))[sub];
        float y0 = wsh[wv][kb * 4 + hh];
        float y1 = wsh[wv][(kb + 2) * 4 + hh];
        float y2 = wsh[wv][(kb + 4) * 4 + hh];
        float y3 = wsh[wv][(kb + 6) * 4 + hh];
        quad_fma(a0, a1, a2, a3, u0, w0);
        quad_fma(a0, a1, a2, a3, u1, w1);
        quad_fma(a0, a1, a2, a3, u2, w2);
        quad_fma(a0, a1, a2, a3, u3, w3);
        u0 = v0; u1 = v1; u2 = v2; u3 = v3;
        w0 = y0; w1 = y1; w2 = y2; w3 = y3;
      }
      quad_fma(a0, a1, a2, a3, u0, w0);
      quad_fma(a0, a1, a2, a3, u1, w1);
      quad_fma(a0, a1, a2, a3, u2, w2);
      quad_fma(a0, a1, a2, a3, u3, w3);
      k = G * 8;
    }
    for (; k < deg; k += 2) {
      int ke = k + half;
      int sk = ssh[wv][ke];
      uint4 u = ((const uint4*)(featb + ((size_t)sk << 8)))[sub];
      float wk = wsh[wv][ke * 4 + hh];
      quad_fma(a0, a1, a2, a3, u, wk);
    }
    a0[0] += __shfl_xor(a0[0], 32); a0[1] += __shfl_xor(a0[1], 32);
    a1[0] += __shfl_xor(a1[0], 32); a1[1] += __shfl_xor(a1[1], 32);
    a2[0] += __shfl_xor(a2[0], 32); a2[1] += __shfl_xor(a2[1], 32);
    a3[0] += __shfl_xor(a3[0], 32); a3[1] += __shfl_xor(a3[1], 32);

    if (half == 0) {
      size_t base = (size_t)node * 256 + sub * 8;
      float v0 = a0[0], v1 = a0[1], v2 = a1[0], v3 = a1[1];
      float v4 = a2[0], v5 = a2[1], v6 = a3[0], v7 = a3[1];
      float4 b0 = *(const float4*)(bias + sub * 8);
      float4 b1 = *(const float4*)(bias + sub * 8 + 4);
      v0 += b0.x; v1 += b0.y; v2 += b0.z; v3 += b0.w;
      v4 += b1.x; v5 += b1.y; v6 += b1.z; v7 += b1.w;
      if (RES) {
        uint4 r = *(const uint4*)(hinb + base);
        v0 += bflo(r.x); v1 += bfhi(r.x);
        v2 += bflo(r.y); v3 += bfhi(r.y);
        v4 += bflo(r.z); v5 += bfhi(r.z);
        v6 += bflo(r.w); v7 += bfhi(r.w);
      }
      uint4 o;
      o.x = pk2(eluf(v0), eluf(v1));
      o.y = pk2(eluf(v2), eluf(v3));
      o.z = pk2(eluf(v4), eluf(v5));
      o.w = pk2(eluf(v6), eluf(v7));
      *(uint4*)(houtb + base) = o;
    }
  } else {
    int hsel = lane >> 4;
    f32x2_t a01 = {0.f, 0.f}, a23 = {0.f, 0.f};
    float m0 = -INFINITY, m1 = -INFINITY, m2 = -INFINITY, m3 = -INFINITY;
    for (int k = s0 + lane; k < s1; k += 64) {
      int s = csrc[k];
      float4 e = *(const float4*)(el + (size_t)s * 4);
      m0 = fmaxf(m0, leaky(e.x + erv.x));
      m1 = fmaxf(m1, leaky(e.y + erv.y));
      m2 = fmaxf(m2, leaky(e.z + erv.z));
      m3 = fmaxf(m3, leaky(e.w + erv.w));
    }
    m0 = wmax(m0); m1 = wmax(m1); m2 = wmax(m2); m3 = wmax(m3);
    float d0 = 0, d1 = 0, d2 = 0, d3 = 0;
    for (int k = s0 + lane; k < s1; k += 64) {
      int s = csrc[k];
      float4 e = *(const float4*)(el + (size_t)s * 4);
      d0 += __expf(leaky(e.x + erv.x) - m0);
      d1 += __expf(leaky(e.y + erv.y) - m1);
      d2 += __expf(leaky(e.z + erv.z) - m2);
      d3 += __expf(leaky(e.w + erv.w) - m3);
    }
    d0 = wsum_sh(d0); d1 = wsum_sh(d1); d2 = wsum_sh(d2); d3 = wsum_sh(d3);
    float j0 = d0 > 0.f ? 1.f / d0 : 0.f;
    float j1 = d1 > 0.f ? 1.f / d1 : 0.f;
    float j2 = d2 > 0.f ? 1.f / d2 : 0.f;
    float j3 = d3 > 0.f ? 1.f / d3 : 0.f;
    for (int k = s0; k < s1; ++k) {
      int s = csrc[k];
      float4 e = *(const float4*)(el + (size_t)s * 4);
      float w0 = __expf(leaky(e.x + erv.x) - m0) * j0;
      float w1 = __expf(leaky(e.y + erv.y) - m1) * j1;
      float w2 = __expf(leaky(e.z + erv.z) - m2) * j2;
      float w3 = __expf(leaky(e.w + erv.w) - m3) * j3;
      float wk = (hsel == 0) ? w0 : (hsel == 1) ? w1 : (hsel == 2) ? w2 : w3;
      uint2 u = ((const uint2*)(featb + ((size_t)s << 8)))[lane];
      f32x2_t wv2 = {wk, wk};
      f32x2_t f;
      f[0] = bflo(u.x); f[1] = bfhi(u.x); a01 = __builtin_elementwise_fma(wv2, f, a01);
      f[0] = bflo(u.y); f[1] = bfhi(u.y); a23 = __builtin_elementwise_fma(wv2, f, a23);
    }
    size_t base = (size_t)node * 256 + lane * 4;
    float4 bv = *(const float4*)(bias + lane * 4);
    float v0 = a01[0] + bv.x, v1 = a01[1] + bv.y;
    float v2 = a23[0] + bv.z, v3 = a23[1] + bv.w;
    if (RES) {
      uint2 r = *(const uint2*)(hinb + base);
      v0 += bflo(r.x); v1 += bfhi(r.x);
      v2 += bflo(r.y); v3 += bfhi(r.y);
    }
    uint2 o;
    o.x = pk2(eluf(v0), eluf(v1));
    o.y = pk2(eluf(v2), eluf(v3));
    *(uint2*)(houtb + base) = o;
  }
}

// ---------------- layer 4 projection (MFMA) + el4/er4 epilogue ----------------
__global__ __launch_bounds__(256) void l4mfma_k(const __hip_bfloat16* __restrict__ hb,
                                                const __hip_bfloat16* __restrict__ Wcat,
                                                const float* __restrict__ al4,
                                                const float* __restrict__ ar4,
                                                float* __restrict__ feat4,
                                                float* __restrict__ res4,
                                                float* __restrict__ el4,
                                                float* __restrict__ er4, int n) {
  int wid = blockIdx.x * 4 + (threadIdx.x >> 6);
  int n16 = (n + 15) >> 4;
  if (wid >= n16) return;
  int lane = threadIdx.x & 63;
  int tm = lane & 15, tq = lane >> 4;
  int row = wid * 16 + tm;
  int rowc = row < n ? row : n - 1;
  const __hip_bfloat16* ap = hb + (size_t)rowc * 256 + tq * 8;
  const __hip_bfloat16* bp = Wcat + (size_t)tm * 256 + tq * 8;
  f32x4_t acc = {0.f, 0.f, 0.f, 0.f};
#pragma unroll
  for (int k = 0; k < 8; ++k) {
    bf16x8_t af = *(const bf16x8_t*)(ap + k * 32);
    bf16x8_t bf = *(const bf16x8_t*)(bp + k * 32);
    acc = __builtin_amdgcn_mfma_f32_16x16x32_bf16(af, bf, acc, 0, 0, 0);
  }
  float* dstp = (tm < 8) ? feat4 : res4;
  int cc = tm & 7;
  float a4 = (tm < 8) ? al4[tm] : 0.f;
  float r4 = (tm < 8) ? ar4[tm] : 0.f;
#pragma unroll
  for (int r = 0; r < 4; ++r) {
    int node = wid * 16 + tq * 4 + r;
    float te = acc[r] * a4;
    float tr = acc[r] * r4;
    te += __shfl_xor(te, 1);
    tr += __shfl_xor(tr, 1);
    if (node < n) {
      dstp[(size_t)node * 8 + cc] = acc[r];
      if (tm < 8 && (tm & 1) == 0) {
        el4[(size_t)node * 4 + (tm >> 1)] = te;
        er4[(size_t)node * 4 + (tm >> 1)] = tr;
      }
    }
  }
}

// ---------------- layer 4 aggregate ----------------
__global__ __launch_bounds__(256) void agg4_k(const float* __restrict__ feat4,
                                              const float* __restrict__ el4,
                                              const float* __restrict__ er4,
                                              const int* __restrict__ rowp,
                                              const int* __restrict__ csrc,
                                              const float* __restrict__ res4,
                                              const float* __restrict__ b4,
                                              float* __restrict__ out, int n) {
  int wv = threadIdx.x >> 6;
  int node = blockIdx.x * 4 + wv;
  int lane = threadIdx.x & 63;
  if (node >= n) return;
  int s0 = rowp[node], s1 = rowp[node + 1];
  int deg = s1 - s0;
  float4 erv = *(const float4*)(er4 + (size_t)node * 4);
  float v = 0.f;

  if (deg <= 64) {
    int sown = 0;
    float x0 = 0.f, x1 = 0.f, x2 = 0.f, x3 = 0.f;
    if (lane < deg) {
      sown = csrc[s0 + lane];
      float4 e = *(const float4*)(el4 + (size_t)sown * 4);
      x0 = __expf(leaky(e.x + erv.x));
      x1 = __expf(leaky(e.y + erv.y));
      x2 = __expf(leaky(e.z + erv.z));
      x3 = __expf(leaky(e.w + erv.w));
    }
    float d0 = wsum_dpp(x0), d1 = wsum_dpp(x1), d2 = wsum_dpp(x2), d3 = wsum_dpp(x3);
    float w0 = x0 * (d0 > 0.f ? 1.f / d0 : 0.f);
    float w1 = x1 * (d1 > 0.f ? 1.f / d1 : 0.f);
    float w2 = x2 * (d2 > 0.f ? 1.f / d2 : 0.f);
    float w3 = x3 * (d3 > 0.f ? 1.f / d3 : 0.f);
    float4 f0 = {0, 0, 0, 0}, f1 = {0, 0, 0, 0};
    if (lane < deg) {
      const float4* fp = (const float4*)(feat4 + (size_t)sown * 8);
      f0 = fp[0];
      f1 = fp[1];
    }
    float t0 = w0 * f0.x, t1 = w0 * f0.y;
    float t2 = w1 * f0.z, t3 = w1 * f0.w;
    float t4 = w2 * f1.x, t5 = w2 * f1.y;
    float t6 = w3 * f1.z, t7 = w3 * f1.w;
    t0 = wsum_dpp(t0); t1 = wsum_dpp(t1); t2 = wsum_dpp(t2); t3 = wsum_dpp(t3);
    t4 = wsum_dpp(t4); t5 = wsum_dpp(t5); t6 = wsum_dpp(t6); t7 = wsum_dpp(t7);
    int p = lane & 7;
    float s = t0;
    s = (p == 1) ? t1 : s; s = (p == 2) ? t2 : s; s = (p == 3) ? t3 : s;
    s = (p == 4) ? t4 : s; s = (p == 5) ? t5 : s; s = (p == 6) ? t6 : s;
    s = (p == 7) ? t7 : s;
    if (lane < 8) v = s + res4[(size_t)node * 8 + lane] + b4[lane];
  } else {
    int p = lane & 7, hh = p >> 1;
    float acc = 0.f;
    float m0 = -INFINITY, m1 = -INFINITY, m2 = -INFINITY, m3 = -INFINITY;
    for (int k = s0 + lane; k < s1; k += 64) {
      int s = csrc[k];
      float4 e = *(const float4*)(el4 + (size_t)s * 4);
      m0 = fmaxf(m0, leaky(e.x + erv.x));
      m1 = fmaxf(m1, leaky(e.y + erv.y));
      m2 = fmaxf(m2, leaky(e.z + erv.z));
      m3 = fmaxf(m3, leaky(e.w + erv.w));
    }
    m0 = wmax(m0); m1 = wmax(m1); m2 = wmax(m2); m3 = wmax(m3);
    float d0 = 0, d1 = 0, d2 = 0, d3 = 0;
    for (int k = s0 + lane; k < s1; k += 64) {
      int s = csrc[k];
      float4 e = *(const float4*)(el4 + (size_t)s * 4);
      d0 += __expf(leaky(e.x + erv.x) - m0);
      d1 += __expf(leaky(e.y + erv.y) - m1);
      d2 += __expf(leaky(e.z + erv.z) - m2);
      d3 += __expf(leaky(e.w + erv.w) - m3);
    }
    d0 = wsum_sh(d0); d1 = wsum_sh(d1); d2 = wsum_sh(d2); d3 = wsum_sh(d3);
    float i0 = d0 > 0.f ? 1.f / d0 : 0.f;
    float i1 = d1 > 0.f ? 1.f / d1 : 0.f;
    float i2 = d2 > 0.f ? 1.f / d2 : 0.f;
    float i3 = d3 > 0.f ? 1.f / d3 : 0.f;
    for (int k = s0; k < s1; ++k) {
      int s = csrc[k];
      float4 e = *(const float4*)(el4 + (size_t)s * 4);
      float w0 = __expf(leaky(e.x + erv.x) - m0) * i0;
      float w1 = __expf(leaky(e.y + erv.y) - m1) * i1;
      float w2 = __expf(leaky(e.z + erv.z) - m2) * i2;
      float w3 = __expf(leaky(e.w + erv.w) - m3) * i3;
      float wk = (hh == 0) ? w0 : (hh == 1) ? w1 : (hh == 2) ? w2 : w3;
      if (lane < 8) acc = fmaf(wk, feat4[(size_t)s * 8 + p], acc);
    }
    if (lane < 8) v = acc + res4[(size_t)node * 8 + lane] + b4[lane];
  }

  float pv = __shfl_xor(v, 1);
  float mx = fmaxf(v, pv);
  float ex = __expf(v - mx);
  float sm = ex + __shfl_xor(ex, 1);
  float pr = ex / sm;
  float t = pr + __shfl_xor(pr, 2);
  t += __shfl_xor(t, 4);
  if (lane < 2) out[(size_t)node * 2 + lane] = t * 0.25f;
}

extern "C" void kernel_launch(void* const* d_in, const int* in_sizes, int n_in,
                              void* d_out, int out_size, void* d_ws, size_t ws_size,
                              hipStream_t stream) {
  const float* x   = (const float*)d_in[0];
  const int* src   = (const int*)d_in[1];
  const int* dst   = (const int*)d_in[2];
  const float* W1  = (const float*)d_in[3];
  const float* al1 = (const float*)d_in[4];
  const float* ar1 = (const float*)d_in[5];
  const float* b1  = (const float*)d_in[6];
  const float* W2  = (const float*)d_in[7];
  const float* al2 = (const float*)d_in[8];
  const float* ar2 = (const float*)d_in[9];
  const float* b2  = (const float*)d_in[10];
  const float* W3  = (const float*)d_in[11];
  const float* al3 = (const float*)d_in[12];
  const float* ar3 = (const float*)d_in[13];
  const float* b3  = (const float*)d_in[14];
  const float* W4  = (const float*)d_in[15];
  const float* al4 = (const float*)d_in[16];
  const float* ar4 = (const float*)d_in[17];
  const float* b4  = (const float*)d_in[18];
  const float* rW4 = (const float*)d_in[19];
  float* out = (float*)d_out;

  const int n = in_sizes[0] / 128;  // 50000
  const int e = in_sizes[1];        // 800000

  char* ws = (char*)d_ws;
  auto alloc = [&](size_t bytes) -> char* {
    char* p = ws;
    ws += (bytes + 255) & ~(size_t)255;
    return p;
  };
  __hip_bfloat16* featb = (__hip_bfloat16*)alloc((size_t)n * 256 * 2);
  __hip_bfloat16* h1b   = (__hip_bfloat16*)alloc((size_t)n * 256 * 2);
  __hip_bfloat16* h2b   = (__hip_bfloat16*)alloc((size_t)n * 256 * 2);
  __hip_bfloat16* h3b   = (__hip_bfloat16*)alloc((size_t)n * 256 * 2);
  __hip_bfloat16* W1b   = (__hip_bfloat16*)alloc((size_t)256 * 128 * 2);
  __hip_bfloat16* W2b   = (__hip_bfloat16*)alloc((size_t)256 * 256 * 2);
  __hip_bfloat16* W3b   = (__hip_bfloat16*)alloc((size_t)256 * 256 * 2);
  __hip_bfloat16* Wcatb = (__hip_bfloat16*)alloc((size_t)16 * 256 * 2);
  float* el    = (float*)alloc((size_t)n * 4 * 4);
  float* er    = (float*)alloc((size_t)n * 4 * 4);
  float* feat4 = (float*)alloc((size_t)n * 8 * 4);
  float* res4  = (float*)alloc((size_t)n * 8 * 4);
  float* el4   = (float*)alloc((size_t)n * 4 * 4);
  float* er4   = (float*)alloc((size_t)n * 4 * 4);
  int* deg     = (int*)alloc((size_t)n * 4);
  int* rowp    = (int*)alloc((size_t)(n + 1) * 4);
  int* rowpf   = (int*)alloc((size_t)(n + 1) * 4);
  int* csrc    = (int*)alloc((size_t)e * 4);
  int* slot    = (int*)alloc((size_t)e * 4);
  int* bsum    = (int*)alloc((size_t)64 * 4);
  int* bpre    = (int*)alloc((size_t)66 * 4);
  int* cnt     = (int*)alloc((size_t)256 * 4);  // cnt[128] + rel[128]
  int* rel     = cnt + 128;

  (void)hipMemsetAsync(cnt, 0, 256 * 4, stream);

  csr_k<<<512, 256, 0, stream>>>(W1, W2, W3, W4, rW4, W1b, W2b, W3b, Wcatb,
                                 src, dst, deg, slot, rowp, rowpf, bsum, bpre,
                                 csrc, cnt, rel, n, e);

  int nbx = (n + 127) / 128;
  int ggx = ((2 * nbx + 15) / 16) * 16;
  int nb4 = (n + 3) / 4;

  // layer 1 (f32 x read directly)
  gemm1f_mfma<<<ggx, 256, 0, stream>>>(x, W1b, featb, al1, ar1, el, er, n, nbx);
  agg64_k<0><<<nb4, 256, 0, stream>>>(featb, el, er, rowpf, csrc, nullptr, b1, h1b, n);
  // layer 2
  gemm_mfma<256><<<ggx, 256, 0, stream>>>(h1b, W2b, featb, al2, ar2, el, er, n, nbx);
  agg64_k<1><<<nb4, 256, 0, stream>>>(featb, el, er, rowpf, csrc, h1b, b2, h2b, n);
  // layer 3
  gemm_mfma<256><<<ggx, 256, 0, stream>>>(h2b, W3b, featb, al3, ar3, el, er, n, nbx);
  agg64_k<1><<<nb4, 256, 0, stream>>>(featb, el, er, rowpf, csrc, h2b, b3, h3b, n);
  // layer 4
  int n16 = (n + 15) / 16;
  l4mfma_k<<<(n16 + 3) / 4, 256, 0, stream>>>(h3b, Wcatb, al4, ar4, feat4, res4, el4, er4, n);
  agg4_k<<<nb4, 256, 0, stream>>>(feat4, el4, er4, rowpf, csrc, res4, b4, out, n);
}

// Round 9
// 440.409 us; speedup vs baseline: 2.0434x; 2.0434x over previous
//
#include <hip/hip_runtime.h>
#include <hip/hip_bf16.h>
#include <math.h>

// GAT, 4 layers: N=50000, E=800000, IN=128, HID=64, H=4, C=2.
// R13 481.9 -> R15 474.6 -> R17 449.6 (BEST). agg64 x3=205us CLOSED.
// R18/R19 persistent-CSR FAILED (772/900us): device-wide spin barriers are
// structurally bad on MI355X (single-line: RMW starvation; striped+sleep:
// still 523us @ 0.15% VALU). CLOSED — no spin barriers; dispatch boundaries
// only. CSR chain measured at 67us (R18 attribution), real work ~28us.
// R21: revert to R17 structure + fuse scatter as tail blocks of the gemm1f
// launch (deps: scatter needs rowp/slot from scan23 which precedes gemm1;
// agg64 needs csrc+featb, both done at gemm1f boundary). 13 -> 12 dispatches,
// scatter overlaps gemm1's MFMA. Diagnostic: ~450 => gaps nil, dark matter
// is in-kernel -> gemm disasm next; ~435 => keep fusing.

#define LEAKY_SLOPE 0.2f

typedef __bf16 bf16x8_t __attribute__((ext_vector_type(8)));
typedef float f32x4_t __attribute__((ext_vector_type(4)));
typedef float f32x2_t __attribute__((ext_vector_type(2)));

__device__ __forceinline__ float leaky(float x) { return x > 0.f ? x : LEAKY_SLOPE * x; }
__device__ __forceinline__ float eluf(float x)  { return x > 0.f ? x : expm1f(x); }
__device__ __forceinline__ float bflo(unsigned u) { return __uint_as_float(u << 16); }
__device__ __forceinline__ float bfhi(unsigned u) { return __uint_as_float(u & 0xffff0000u); }
__device__ __forceinline__ unsigned pk2(float a, float b) {
  __hip_bfloat162 t;
  t.x = __float2bfloat16(a);
  t.y = __float2bfloat16(b);
  return *(unsigned*)&t;
}

__device__ __forceinline__ float rlf(float v, int l) {
  return __uint_as_float((unsigned)__builtin_amdgcn_readlane((int)__float_as_uint(v), l));
}
template <int CTRL>
__device__ __forceinline__ float dpp_add(float x) {
  int t = __builtin_amdgcn_update_dpp(0, (int)__float_as_uint(x), CTRL, 0xf, 0xf, false);
  return x + __uint_as_float((unsigned)t);
}
__device__ __forceinline__ float wsum_dpp(float x) {
  x = dpp_add<0x111>(x);
  x = dpp_add<0x112>(x);
  x = dpp_add<0x114>(x);
  x = dpp_add<0x118>(x);
  x = dpp_add<0x142>(x);
  x = dpp_add<0x143>(x);
  return rlf(x, 63);
}
__device__ __forceinline__ float rowsum_dpp(float x) {
  x = dpp_add<0x111>(x);
  x = dpp_add<0x112>(x);
  x = dpp_add<0x114>(x);
  x = dpp_add<0x118>(x);
  return x;
}
__device__ __forceinline__ float wmax(float v) {
#pragma unroll
  for (int o = 32; o; o >>= 1) v = fmaxf(v, __shfl_xor(v, o));
  return v;
}
__device__ __forceinline__ float wsum_sh(float v) {
#pragma unroll
  for (int o = 32; o; o >>= 1) v += __shfl_xor(v, o);
  return v;
}

// 8-col fma: u = 8 consecutive bf16 of one head, scalar weight w
__device__ __forceinline__ void quad_fma(f32x2_t& a0, f32x2_t& a1, f32x2_t& a2, f32x2_t& a3,
                                         uint4 u, float w) {
  f32x2_t wv = {w, w};
  f32x2_t f;
  f[0] = bflo(u.x); f[1] = bfhi(u.x); a0 = __builtin_elementwise_fma(wv, f, a0);
  f[0] = bflo(u.y); f[1] = bfhi(u.y); a1 = __builtin_elementwise_fma(wv, f, a1);
  f[0] = bflo(u.z); f[1] = bfhi(u.z); a2 = __builtin_elementwise_fma(wv, f, a2);
  f[0] = bflo(u.w); f[1] = bfhi(u.w); a3 = __builtin_elementwise_fma(wv, f, a3);
}

// async global->LDS, 16B per lane
__device__ __forceinline__ void gl_lds16(const __hip_bfloat16* g, __bf16* l) {
  __builtin_amdgcn_global_load_lds((const __attribute__((address_space(1))) void*)g,
                                   (__attribute__((address_space(3))) void*)l, 16, 0, 0);
}

// ---------------- CSR build ----------------
__global__ __launch_bounds__(1024) void scan1_k(const int* __restrict__ deg,
                                                int* __restrict__ rowp,
                                                int* __restrict__ bsum, int n) {
  __shared__ int wtot[16];
  __shared__ int wpre[16];
  int tid = threadIdx.x, lane = tid & 63, wid = tid >> 6;
  int i = blockIdx.x * 1024 + tid;
  int v = (i < n) ? deg[i] : 0;
  int x = v;
#pragma unroll
  for (int off = 1; off < 64; off <<= 1) {
    int t = __shfl_up(x, off);
    if (lane >= off) x += t;
  }
  if (lane == 63) wtot[wid] = x;
  __syncthreads();
  if (wid == 0 && lane < 16) {
    int s = wtot[lane];
    int y = s;
#pragma unroll
    for (int off = 1; off < 16; off <<= 1) {
      int t = __shfl_up(y, off);
      if (lane >= off) y += t;
    }
    wpre[lane] = y - s;
    if (lane == 15) bsum[blockIdx.x] = y;
  }
  __syncthreads();
  if (i < n) rowp[i] = wpre[wid] + x - v;
}

__global__ void scan23_k(const int* __restrict__ bsum, int* __restrict__ rowp, int n, int nb) {
  __shared__ int pref[65];
  int tid = threadIdx.x;
  if (tid < 64) {
    int v = (tid < nb) ? bsum[tid] : 0;
    int x = v;
#pragma unroll
    for (int off = 1; off < 64; off <<= 1) {
      int t = __shfl_up(x, off);
      if (tid >= off) x += t;
    }
    pref[tid] = x - v;
    if (tid == 63) pref[64] = x;
  }
  __syncthreads();
  int i = blockIdx.x * 256 + tid;
  if (i < n) rowp[i] += pref[i >> 10];
  if (i == n) rowp[n] = pref[64];
}

// ---------------- prep: dst histogram (slot capture) + weight cvt ----------------
__global__ void cvthist_k(const float* __restrict__ W1, const float* __restrict__ W2,
                          const float* __restrict__ W3, const float* __restrict__ W4,
                          const float* __restrict__ rW4,
                          __hip_bfloat16* __restrict__ W1b, __hip_bfloat16* __restrict__ W2b,
                          __hip_bfloat16* __restrict__ W3b, __hip_bfloat16* __restrict__ Wcatb,
                          const int* __restrict__ dst, int* __restrict__ deg,
                          int* __restrict__ slot, int e) {
  int i = blockIdx.x * 256 + threadIdx.x;
  if (i < e) {
    int p = atomicAdd(&deg[dst[i]], 1);
    slot[i] = p;
  }
  if (i < 41984) {
    const float* sp;
    __hip_bfloat16* dp;
    int idx;
    if (i < 8192)       { sp = W1;  dp = W1b;          idx = i; }
    else if (i < 24576) { sp = W2;  dp = W2b;          idx = i - 8192; }
    else if (i < 40960) { sp = W3;  dp = W3b;          idx = i - 24576; }
    else if (i < 41472) { sp = W4;  dp = Wcatb;        idx = i - 40960; }
    else                { sp = rW4; dp = Wcatb + 2048; idx = i - 41472; }
    float4 wv = ((const float4*)sp)[idx];
    uint2 o = {pk2(wv.x, wv.y), pk2(wv.z, wv.w)};
    ((uint2*)dp)[idx] = o;
  }
}

// ---------------- layer-1 GEMM (f32 A, reg-stage cvt) + fused scatter tail ----------------
// Blocks [0, ngemm): GEMM. Blocks [ngemm, ngemm+nsc): scatter
// csrc[rowp[dst]+slot] = src (rowp finalized by scan23, which precedes this launch).
__global__ __launch_bounds__(256) void gemm1f_mfma(const float* __restrict__ A,
                                                   const __hip_bfloat16* __restrict__ B,
                                                   __hip_bfloat16* __restrict__ featb,
                                                   const float* __restrict__ al,
                                                   const float* __restrict__ ar,
                                                   float* __restrict__ el,
                                                   float* __restrict__ er, int n, int nbx,
                                                   int ngemm,
                                                   const int* __restrict__ src,
                                                   const int* __restrict__ dst,
                                                   const int* __restrict__ rowp,
                                                   const int* __restrict__ slot,
                                                   int* __restrict__ csrc, int e) {
  const int wg = blockIdx.x;
  if (wg >= ngemm) {
    int i = (wg - ngemm) * 256 + threadIdx.x;
    if (i < e) csrc[rowp[dst[i]] + slot[i]] = src[i];
    return;
  }
  __shared__ __bf16 As[2][128 * 32];
  __shared__ __bf16 Bs[2][128 * 32];
  const int b = ((wg >> 4) << 3) + (wg & 7);
  if (b >= nbx) return;
  const int cb = (wg >> 3) & 1;
  const int r0 = b * 128, c0 = cb * 128;

  const int tid = threadIdx.x;
  const int lane = tid & 63, w = tid >> 6;
  const int tm = lane & 15, tq = lane >> 4;
  const int wm = (w & 1) * 64, wn = (w >> 1) * 64;

  f32x4_t acc[4][4];
#pragma unroll
  for (int i = 0; i < 4; ++i)
#pragma unroll
    for (int j = 0; j < 4; ++j) acc[i][j] = 0.f;

  const int srow = tid >> 1;
  const int sh = tid & 1;
  const int arw = r0 + srow;
  const bool aok = arw < n;
  const float* ap = A + (size_t)arw * 128 + sh * 32;

  const int srB = w * 32 + (lane >> 2);
  const int scB = (lane & 3) * 8;
  const __hip_bfloat16* gb0 = B + (size_t)(c0 + srB) * 128 + scB;

#pragma unroll
  for (int kk = 0; kk < 128; kk += 64) {
    float4 av0 = {0, 0, 0, 0}, av1 = {0, 0, 0, 0}, av2 = {0, 0, 0, 0}, av3 = {0, 0, 0, 0};
    float4 av4 = {0, 0, 0, 0}, av5 = {0, 0, 0, 0}, av6 = {0, 0, 0, 0}, av7 = {0, 0, 0, 0};
    if (aok) {
      const float4* p = (const float4*)(ap + kk);
      av0 = p[0]; av1 = p[1]; av2 = p[2]; av3 = p[3];
      av4 = p[4]; av5 = p[5]; av6 = p[6]; av7 = p[7];
    }
    __syncthreads();
    const __hip_bfloat16* gbk = gb0 + kk;
    gl_lds16(gbk, &Bs[0][w * 1024]);
    gl_lds16(gbk + (size_t)16 * 128, &Bs[0][w * 1024 + 512]);
    gl_lds16(gbk + 32, &Bs[1][w * 1024]);
    gl_lds16(gbk + (size_t)16 * 128 + 32, &Bs[1][w * 1024 + 512]);
    {
      uint4 o;
      o.x = pk2(av0.x, av0.y); o.y = pk2(av0.z, av0.w);
      o.z = pk2(av1.x, av1.y); o.w = pk2(av1.z, av1.w);
      *(uint4*)&As[sh][srow * 32 + 0] = o;
      o.x = pk2(av2.x, av2.y); o.y = pk2(av2.z, av2.w);
      o.z = pk2(av3.x, av3.y); o.w = pk2(av3.z, av3.w);
      *(uint4*)&As[sh][srow * 32 + 8] = o;
      o.x = pk2(av4.x, av4.y); o.y = pk2(av4.z, av4.w);
      o.z = pk2(av5.x, av5.y); o.w = pk2(av5.z, av5.w);
      *(uint4*)&As[sh][srow * 32 + 16] = o;
      o.x = pk2(av6.x, av6.y); o.y = pk2(av6.z, av6.w);
      o.z = pk2(av7.x, av7.y); o.w = pk2(av7.z, av7.w);
      *(uint4*)&As[sh][srow * 32 + 24] = o;
    }
    __syncthreads();
#pragma unroll
    for (int ks = 0; ks < 2; ++ks) {
      bf16x8_t af[4], bfr[4];
#pragma unroll
      for (int i = 0; i < 4; ++i)
        af[i] = *(const bf16x8_t*)&As[ks][(wm + i * 16 + tm) * 32 + tq * 8];
#pragma unroll
      for (int j = 0; j < 4; ++j)
        bfr[j] = *(const bf16x8_t*)&Bs[ks][(wn + j * 16 + tm) * 32 + tq * 8];
#pragma unroll
      for (int i = 0; i < 4; ++i)
#pragma unroll
        for (int j = 0; j < 4; ++j)
          acc[i][j] = __builtin_amdgcn_mfma_f32_16x16x32_bf16(af[i], bfr[j], acc[i][j], 0, 0, 0);
    }
  }

  // featb store, row-major
#pragma unroll
  for (int i = 0; i < 4; ++i) {
#pragma unroll
    for (int j = 0; j < 4; ++j) {
      int col = c0 + wn + j * 16 + tm;
#pragma unroll
      for (int rr = 0; rr < 4; ++rr) {
        int row = r0 + wm + i * 16 + tq * 4 + rr;
        if (row < n) featb[(size_t)row * 256 + col] = __float2bfloat16(acc[i][j][rr]);
      }
    }
  }

  // el/er epilogue
  {
    const int hd = (c0 + wn) >> 6;
    float alv[4], arv[4];
#pragma unroll
    for (int j = 0; j < 4; ++j) {
      alv[j] = al[hd * 64 + j * 16 + tm];
      arv[j] = ar[hd * 64 + j * 16 + tm];
    }
#pragma unroll
    for (int i = 0; i < 4; ++i) {
#pragma unroll
      for (int rr = 0; rr < 4; ++rr) {
        float se = acc[i][0][rr] * alv[0] + acc[i][1][rr] * alv[1] +
                   acc[i][2][rr] * alv[2] + acc[i][3][rr] * alv[3];
        float sr2 = acc[i][0][rr] * arv[0] + acc[i][1][rr] * arv[1] +
                    acc[i][2][rr] * arv[2] + acc[i][3][rr] * arv[3];
        se = rowsum_dpp(se);
        sr2 = rowsum_dpp(sr2);
        if (tm == 15) {
          int row = r0 + wm + i * 16 + tq * 4 + rr;
          if (row < n) {
            el[(size_t)row * 4 + hd] = se;
            er[(size_t)row * 4 + hd] = sr2;
          }
        }
      }
    }
  }
}

// ---------------- MFMA GEMM (bf16 A), layers 2-3 ----------------
template <int K>
__global__ __launch_bounds__(256) void gemm_mfma(const __hip_bfloat16* __restrict__ A,
                                                 const __hip_bfloat16* __restrict__ B,
                                                 __hip_bfloat16* __restrict__ featb,
                                                 const float* __restrict__ al,
                                                 const float* __restrict__ ar,
                                                 float* __restrict__ el,
                                                 float* __restrict__ er, int n, int nbx) {
  __shared__ __bf16 As[2][128 * 32];
  __shared__ __bf16 Bs[2][128 * 32];
  const int wg = blockIdx.x;
  const int b = ((wg >> 4) << 3) + (wg & 7);
  if (b >= nbx) return;
  const int cb = (wg >> 3) & 1;
  const int r0 = b * 128, c0 = cb * 128;

  const int tid = threadIdx.x;
  const int lane = tid & 63, w = tid >> 6;
  const int tm = lane & 15, tq = lane >> 4;
  const int wm = (w & 1) * 64, wn = (w >> 1) * 64;

  f32x4_t acc[4][4];
#pragma unroll
  for (int i = 0; i < 4; ++i)
#pragma unroll
    for (int j = 0; j < 4; ++j) acc[i][j] = 0.f;

  const bool interior = (r0 + 128 <= n);
  if (interior) {
    const int srow = w * 32 + (lane >> 2);
    const int scol = (lane & 3) * 8;
    const __hip_bfloat16* ga0 = A + (size_t)(r0 + srow) * K + scol;
    const __hip_bfloat16* gb0 = B + (size_t)(c0 + srow) * K + scol;
    for (int kk = 0; kk < K; kk += 64) {
      const __hip_bfloat16* ga = ga0 + kk;
      const __hip_bfloat16* gb = gb0 + kk;
      __syncthreads();
      gl_lds16(ga, &As[0][w * 1024]);
      gl_lds16(ga + (size_t)16 * K, &As[0][w * 1024 + 512]);
      gl_lds16(ga + 32, &As[1][w * 1024]);
      gl_lds16(ga + (size_t)16 * K + 32, &As[1][w * 1024 + 512]);
      gl_lds16(gb, &Bs[0][w * 1024]);
      gl_lds16(gb + (size_t)16 * K, &Bs[0][w * 1024 + 512]);
      gl_lds16(gb + 32, &Bs[1][w * 1024]);
      gl_lds16(gb + (size_t)16 * K + 32, &Bs[1][w * 1024 + 512]);
      __syncthreads();
#pragma unroll
      for (int ks = 0; ks < 2; ++ks) {
        bf16x8_t af[4], bfr[4];
#pragma unroll
        for (int i = 0; i < 4; ++i)
          af[i] = *(const bf16x8_t*)&As[ks][(wm + i * 16 + tm) * 32 + tq * 8];
#pragma unroll
        for (int j = 0; j < 4; ++j)
          bfr[j] = *(const bf16x8_t*)&Bs[ks][(wn + j * 16 + tm) * 32 + tq * 8];
#pragma unroll
        for (int i = 0; i < 4; ++i)
#pragma unroll
          for (int j = 0; j < 4; ++j)
            acc[i][j] = __builtin_amdgcn_mfma_f32_16x16x32_bf16(af[i], bfr[j], acc[i][j], 0, 0, 0);
      }
    }
  } else {
    const int srow = tid >> 1, sko = (tid & 1) * 16;
    for (int kk = 0; kk < K; kk += 32) {
      uint4 av0 = {0, 0, 0, 0}, av1 = {0, 0, 0, 0};
      int arw = r0 + srow;
      if (arw < n) {
        const uint4* p = (const uint4*)(A + (size_t)arw * K + kk + sko);
        av0 = p[0];
        av1 = p[1];
      }
      const uint4* q = (const uint4*)(B + (size_t)(c0 + srow) * K + kk + sko);
      uint4 bv0 = q[0], bv1 = q[1];
      __syncthreads();
      *(uint4*)&As[0][srow * 32 + sko] = av0;
      *(uint4*)&As[0][srow * 32 + sko + 8] = av1;
      *(uint4*)&Bs[0][srow * 32 + sko] = bv0;
      *(uint4*)&Bs[0][srow * 32 + sko + 8] = bv1;
      __syncthreads();
      bf16x8_t af[4], bfr[4];
#pragma unroll
      for (int i = 0; i < 4; ++i)
        af[i] = *(const bf16x8_t*)&As[0][(wm + i * 16 + tm) * 32 + tq * 8];
#pragma unroll
      for (int j = 0; j < 4; ++j)
        bfr[j] = *(const bf16x8_t*)&Bs[0][(wn + j * 16 + tm) * 32 + tq * 8];
#pragma unroll
      for (int i = 0; i < 4; ++i)
#pragma unroll
        for (int j = 0; j < 4; ++j)
          acc[i][j] = __builtin_amdgcn_mfma_f32_16x16x32_bf16(af[i], bfr[j], acc[i][j], 0, 0, 0);
    }
  }

  // featb store, row-major
#pragma unroll
  for (int i = 0; i < 4; ++i) {
#pragma unroll
    for (int j = 0; j < 4; ++j) {
      int col = c0 + wn + j * 16 + tm;
#pragma unroll
      for (int rr = 0; rr < 4; ++rr) {
        int row = r0 + wm + i * 16 + tq * 4 + rr;
        if (row < n) featb[(size_t)row * 256 + col] = __float2bfloat16(acc[i][j][rr]);
      }
    }
  }

  // el/er epilogue
  {
    const int hd = (c0 + wn) >> 6;
    float alv[4], arv[4];
#pragma unroll
    for (int j = 0; j < 4; ++j) {
      alv[j] = al[hd * 64 + j * 16 + tm];
      arv[j] = ar[hd * 64 + j * 16 + tm];
    }
#pragma unroll
    for (int i = 0; i < 4; ++i) {
#pragma unroll
      for (int rr = 0; rr < 4; ++rr) {
        float se = acc[i][0][rr] * alv[0] + acc[i][1][rr] * alv[1] +
                   acc[i][2][rr] * alv[2] + acc[i][3][rr] * alv[3];
        float sr2 = acc[i][0][rr] * arv[0] + acc[i][1][rr] * arv[1] +
                    acc[i][2][rr] * arv[2] + acc[i][3][rr] * arv[3];
        se = rowsum_dpp(se);
        sr2 = rowsum_dpp(sr2);
        if (tm == 15) {
          int row = r0 + wm + i * 16 + tq * 4 + rr;
          if (row < n) {
            el[(size_t)row * 4 + hd] = se;
            er[(size_t)row * 4 + hd] = sr2;
          }
        }
      }
    }
  }
}

// ---------------- aggregate layers 1-3 (at random-gather service wall) ----------------
template <int RES>
__global__ __launch_bounds__(256) void agg64_k(const __hip_bfloat16* __restrict__ featb,
                                               const float* __restrict__ el,
                                               const float* __restrict__ er,
                                               const int* __restrict__ rowp,
                                               const int* __restrict__ csrc,
                                               const __hip_bfloat16* __restrict__ hinb,
                                               const float* __restrict__ bias,
                                               __hip_bfloat16* __restrict__ houtb, int n) {
  __shared__ float wsh[4][256];
  __shared__ int ssh[4][64];
  int wv = threadIdx.x >> 6;
  int node = blockIdx.x * 4 + wv;
  int lane = threadIdx.x & 63;
  if (node >= n) return;
  int s0 = rowp[node], s1 = rowp[node + 1];
  int deg = s1 - s0;
  float4 erv = *(const float4*)(er + (size_t)node * 4);

  if (deg <= 64) {
    int sown = 0;
    float x0 = 0.f, x1 = 0.f, x2 = 0.f, x3 = 0.f;
    if (lane < deg) {
      sown = csrc[s0 + lane];
      float4 e = *(const float4*)(el + (size_t)sown * 4);
      x0 = __expf(leaky(e.x + erv.x));
      x1 = __expf(leaky(e.y + erv.y));
      x2 = __expf(leaky(e.z + erv.z));
      x3 = __expf(leaky(e.w + erv.w));
    }
    float d0 = wsum_dpp(x0), d1 = wsum_dpp(x1), d2 = wsum_dpp(x2), d3 = wsum_dpp(x3);
    float i0 = d0 > 0.f ? 1.f / d0 : 0.f;
    float i1 = d1 > 0.f ? 1.f / d1 : 0.f;
    float i2 = d2 > 0.f ? 1.f / d2 : 0.f;
    float i3 = d3 > 0.f ? 1.f / d3 : 0.f;
    float4 wq = {x0 * i0, x1 * i1, x2 * i2, x3 * i3};
    *(float4*)&wsh[wv][lane * 4] = wq;
    ssh[wv][lane] = sown;

    const int half = lane >> 5, sub = lane & 31;
    const int hh = sub >> 3;
    f32x2_t a0 = {0.f, 0.f}, a1 = {0.f, 0.f}, a2 = {0.f, 0.f}, a3 = {0.f, 0.f};
    const int G = deg >> 3;
    int k = 0;
    if (G) {
      int ke = half;
      int sk0 = ssh[wv][ke], sk1 = ssh[wv][ke + 2];
      int sk2 = ssh[wv][ke + 4], sk3 = ssh[wv][ke + 6];
      uint4 u0 = ((const uint4*)(featb + ((size_t)sk0 << 8)))[sub];
      uint4 u1 = ((const uint4*)(featb + ((size_t)sk1 << 8)))[sub];
      uint4 u2 = ((const uint4*)(featb + ((size_t)sk2 << 8)))[sub];
      uint4 u3 = ((const uint4*)(featb + ((size_t)sk3 << 8)))[sub];
      float w0 = wsh[wv][ke * 4 + hh];
      float w1 = wsh[wv][(ke + 2) * 4 + hh];
      float w2 = wsh[wv][(ke + 4) * 4 + hh];
      float w3 = wsh[wv][(ke + 6) * 4 + hh];
      for (int g = 1; g < G; ++g) {
        int kb = g * 8 + half;
        int t0 = ssh[wv][kb], t1 = ssh[wv][kb + 2];
        int t2 = ssh[wv][kb + 4], t3 = ssh[wv][kb + 6];
        uint4 v0 = ((const uint4*)(featb + ((size_t)t0 << 8)))[sub];
        uint4 v1 = ((const uint4*)(featb + ((size_t)t1 << 8)))[sub];
        uint4 v2 = ((const uint4*)(featb + ((size_t)t2 << 8)))[sub];
        uint4 v3 = ((const uint4*)(featb + ((size_t)t3 << 8)))[sub];
        float y0 = wsh[wv][kb * 4 + hh];
        float y1 = wsh[wv][(kb + 2) * 4 + hh];
        float y2 = wsh[wv][(kb + 4) * 4 + hh];
        float y3 = wsh[wv][(kb + 6) * 4 + hh];
        quad_fma(a0, a1, a2, a3, u0, w0);
        quad_fma(a0, a1, a2, a3, u1, w1);
        quad_fma(a0, a1, a2, a3, u2, w2);
        quad_fma(a0, a1, a2, a3, u3, w3);
        u0 = v0; u1 = v1; u2 = v2; u3 = v3;
        w0 = y0; w1 = y1; w2 = y2; w3 = y3;
      }
      quad_fma(a0, a1, a2, a3, u0, w0);
      quad_fma(a0, a1, a2, a3, u1, w1);
      quad_fma(a0, a1, a2, a3, u2, w2);
      quad_fma(a0, a1, a2, a3, u3, w3);
      k = G * 8;
    }
    for (; k < deg; k += 2) {
      int ke = k + half;
      int sk = ssh[wv][ke];
      uint4 u = ((const uint4*)(featb + ((size_t)sk << 8)))[sub];
      float wk = wsh[wv][ke * 4 + hh];
      quad_fma(a0, a1, a2, a3, u, wk);
    }
    a0[0] += __shfl_xor(a0[0], 32); a0[1] += __shfl_xor(a0[1], 32);
    a1[0] += __shfl_xor(a1[0], 32); a1[1] += __shfl_xor(a1[1], 32);
    a2[0] += __shfl_xor(a2[0], 32); a2[1] += __shfl_xor(a2[1], 32);
    a3[0] += __shfl_xor(a3[0], 32); a3[1] += __shfl_xor(a3[1], 32);

    if (half == 0) {
      size_t base = (size_t)node * 256 + sub * 8;
      float v0 = a0[0], v1 = a0[1], v2 = a1[0], v3 = a1[1];
      float v4 = a2[0], v5 = a2[1], v6 = a3[0], v7 = a3[1];
      float4 b0 = *(const float4*)(bias + sub * 8);
      float4 b1 = *(const float4*)(bias + sub * 8 + 4);
      v0 += b0.x; v1 += b0.y; v2 += b0.z; v3 += b0.w;
      v4 += b1.x; v5 += b1.y; v6 += b1.z; v7 += b1.w;
      if (RES) {
        uint4 r = *(const uint4*)(hinb + base);
        v0 += bflo(r.x); v1 += bfhi(r.x);
        v2 += bflo(r.y); v3 += bfhi(r.y);
        v4 += bflo(r.z); v5 += bfhi(r.z);
        v6 += bflo(r.w); v7 += bfhi(r.w);
      }
      uint4 o;
      o.x = pk2(eluf(v0), eluf(v1));
      o.y = pk2(eluf(v2), eluf(v3));
      o.z = pk2(eluf(v4), eluf(v5));
      o.w = pk2(eluf(v6), eluf(v7));
      *(uint4*)(houtb + base) = o;
    }
  } else {
    int hsel = lane >> 4;
    f32x2_t a01 = {0.f, 0.f}, a23 = {0.f, 0.f};
    float m0 = -INFINITY, m1 = -INFINITY, m2 = -INFINITY, m3 = -INFINITY;
    for (int k = s0 + lane; k < s1; k += 64) {
      int s = csrc[k];
      float4 e = *(const float4*)(el + (size_t)s * 4);
      m0 = fmaxf(m0, leaky(e.x + erv.x));
      m1 = fmaxf(m1, leaky(e.y + erv.y));
      m2 = fmaxf(m2, leaky(e.z + erv.z));
      m3 = fmaxf(m3, leaky(e.w + erv.w));
    }
    m0 = wmax(m0); m1 = wmax(m1); m2 = wmax(m2); m3 = wmax(m3);
    float d0 = 0, d1 = 0, d2 = 0, d3 = 0;
    for (int k = s0 + lane; k < s1; k += 64) {
      int s = csrc[k];
      float4 e = *(const float4*)(el + (size_t)s * 4);
      d0 += __expf(leaky(e.x + erv.x) - m0);
      d1 += __expf(leaky(e.y + erv.y) - m1);
      d2 += __expf(leaky(e.z + erv.z) - m2);
      d3 += __expf(leaky(e.w + erv.w) - m3);
    }
    d0 = wsum_sh(d0); d1 = wsum_sh(d1); d2 = wsum_sh(d2); d3 = wsum_sh(d3);
    float j0 = d0 > 0.f ? 1.f / d0 : 0.f;
    float j1 = d1 > 0.f ? 1.f / d1 : 0.f;
    float j2 = d2 > 0.f ? 1.f / d2 : 0.f;
    float j3 = d3 > 0.f ? 1.f / d3 : 0.f;
    for (int k = s0; k < s1; ++k) {
      int s = csrc[k];
      float4 e = *(const float4*)(el + (size_t)s * 4);
      float w0 = __expf(leaky(e.x + erv.x) - m0) * j0;
      float w1 = __expf(leaky(e.y + erv.y) - m1) * j1;
      float w2 = __expf(leaky(e.z + erv.z) - m2) * j2;
      float w3 = __expf(leaky(e.w + erv.w) - m3) * j3;
      float wk = (hsel == 0) ? w0 : (hsel == 1) ? w1 : (hsel == 2) ? w2 : w3;
      uint2 u = ((const uint2*)(featb + ((size_t)s << 8)))[lane];
      f32x2_t wv2 = {wk, wk};
      f32x2_t f;
      f[0] = bflo(u.x); f[1] = bfhi(u.x); a01 = __builtin_elementwise_fma(wv2, f, a01);
      f[0] = bflo(u.y); f[1] = bfhi(u.y); a23 = __builtin_elementwise_fma(wv2, f, a23);
    }
    size_t base = (size_t)node * 256 + lane * 4;
    float4 bv = *(const float4*)(bias + lane * 4);
    float v0 = a01[0] + bv.x, v1 = a01[1] + bv.y;
    float v2 = a23[0] + bv.z, v3 = a23[1] + bv.w;
    if (RES) {
      uint2 r = *(const uint2*)(hinb + base);
      v0 += bflo(r.x); v1 += bfhi(r.x);
      v2 += bflo(r.y); v3 += bfhi(r.y);
    }
    uint2 o;
    o.x = pk2(eluf(v0), eluf(v1));
    o.y = pk2(eluf(v2), eluf(v3));
    *(uint2*)(houtb + base) = o;
  }
}

// ---------------- layer 4 projection (MFMA) + el4/er4 epilogue ----------------
__global__ __launch_bounds__(256) void l4mfma_k(const __hip_bfloat16* __restrict__ hb,
                                                const __hip_bfloat16* __restrict__ Wcat,
                                                const float* __restrict__ al4,
                                                const float* __restrict__ ar4,
                                                float* __restrict__ feat4,
                                                float* __restrict__ res4,
                                                float* __restrict__ el4,
                                                float* __restrict__ er4, int n) {
  int wid = blockIdx.x * 4 + (threadIdx.x >> 6);
  int n16 = (n + 15) >> 4;
  if (wid >= n16) return;
  int lane = threadIdx.x & 63;
  int tm = lane & 15, tq = lane >> 4;
  int row = wid * 16 + tm;
  int rowc = row < n ? row : n - 1;
  const __hip_bfloat16* ap = hb + (size_t)rowc * 256 + tq * 8;
  const __hip_bfloat16* bp = Wcat + (size_t)tm * 256 + tq * 8;
  f32x4_t acc = {0.f, 0.f, 0.f, 0.f};
#pragma unroll
  for (int k = 0; k < 8; ++k) {
    bf16x8_t af = *(const bf16x8_t*)(ap + k * 32);
    bf16x8_t bf = *(const bf16x8_t*)(bp + k * 32);
    acc = __builtin_amdgcn_mfma_f32_16x16x32_bf16(af, bf, acc, 0, 0, 0);
  }
  float* dstp = (tm < 8) ? feat4 : res4;
  int cc = tm & 7;
  float a4 = (tm < 8) ? al4[tm] : 0.f;
  float r4 = (tm < 8) ? ar4[tm] : 0.f;
#pragma unroll
  for (int r = 0; r < 4; ++r) {
    int node = wid * 16 + tq * 4 + r;
    float te = acc[r] * a4;
    float tr = acc[r] * r4;
    te += __shfl_xor(te, 1);
    tr += __shfl_xor(tr, 1);
    if (node < n) {
      dstp[(size_t)node * 8 + cc] = acc[r];
      if (tm < 8 && (tm & 1) == 0) {
        el4[(size_t)node * 4 + (tm >> 1)] = te;
        er4[(size_t)node * 4 + (tm >> 1)] = tr;
      }
    }
  }
}

// ---------------- layer 4 aggregate ----------------
__global__ __launch_bounds__(256) void agg4_k(const float* __restrict__ feat4,
                                              const float* __restrict__ el4,
                                              const float* __restrict__ er4,
                                              const int* __restrict__ rowp,
                                              const int* __restrict__ csrc,
                                              const float* __restrict__ res4,
                                              const float* __restrict__ b4,
                                              float* __restrict__ out, int n) {
  int wv = threadIdx.x >> 6;
  int node = blockIdx.x * 4 + wv;
  int lane = threadIdx.x & 63;
  if (node >= n) return;
  int s0 = rowp[node], s1 = rowp[node + 1];
  int deg = s1 - s0;
  float4 erv = *(const float4*)(er4 + (size_t)node * 4);
  float v = 0.f;

  if (deg <= 64) {
    int sown = 0;
    float x0 = 0.f, x1 = 0.f, x2 = 0.f, x3 = 0.f;
    if (lane < deg) {
      sown = csrc[s0 + lane];
      float4 e = *(const float4*)(el4 + (size_t)sown * 4);
      x0 = __expf(leaky(e.x + erv.x));
      x1 = __expf(leaky(e.y + erv.y));
      x2 = __expf(leaky(e.z + erv.z));
      x3 = __expf(leaky(e.w + erv.w));
    }
    float d0 = wsum_dpp(x0), d1 = wsum_dpp(x1), d2 = wsum_dpp(x2), d3 = wsum_dpp(x3);
    float w0 = x0 * (d0 > 0.f ? 1.f / d0 : 0.f);
    float w1 = x1 * (d1 > 0.f ? 1.f / d1 : 0.f);
    float w2 = x2 * (d2 > 0.f ? 1.f / d2 : 0.f);
    float w3 = x3 * (d3 > 0.f ? 1.f / d3 : 0.f);
    float4 f0 = {0, 0, 0, 0}, f1 = {0, 0, 0, 0};
    if (lane < deg) {
      const float4* fp = (const float4*)(feat4 + (size_t)sown * 8);
      f0 = fp[0];
      f1 = fp[1];
    }
    float t0 = w0 * f0.x, t1 = w0 * f0.y;
    float t2 = w1 * f0.z, t3 = w1 * f0.w;
    float t4 = w2 * f1.x, t5 = w2 * f1.y;
    float t6 = w3 * f1.z, t7 = w3 * f1.w;
    t0 = wsum_dpp(t0); t1 = wsum_dpp(t1); t2 = wsum_dpp(t2); t3 = wsum_dpp(t3);
    t4 = wsum_dpp(t4); t5 = wsum_dpp(t5); t6 = wsum_dpp(t6); t7 = wsum_dpp(t7);
    int p = lane & 7;
    float s = t0;
    s = (p == 1) ? t1 : s; s = (p == 2) ? t2 : s; s = (p == 3) ? t3 : s;
    s = (p == 4) ? t4 : s; s = (p == 5) ? t5 : s; s = (p == 6) ? t6 : s;
    s = (p == 7) ? t7 : s;
    if (lane < 8) v = s + res4[(size_t)node * 8 + lane] + b4[lane];
  } else {
    int p = lane & 7, hh = p >> 1;
    float acc = 0.f;
    float m0 = -INFINITY, m1 = -INFINITY, m2 = -INFINITY, m3 = -INFINITY;
    for (int k = s0 + lane; k < s1; k += 64) {
      int s = csrc[k];
      float4 e = *(const float4*)(el4 + (size_t)s * 4);
      m0 = fmaxf(m0, leaky(e.x + erv.x));
      m1 = fmaxf(m1, leaky(e.y + erv.y));
      m2 = fmaxf(m2, leaky(e.z + erv.z));
      m3 = fmaxf(m3, leaky(e.w + erv.w));
    }
    m0 = wmax(m0); m1 = wmax(m1); m2 = wmax(m2); m3 = wmax(m3);
    float d0 = 0, d1 = 0, d2 = 0, d3 = 0;
    for (int k = s0 + lane; k < s1; k += 64) {
      int s = csrc[k];
      float4 e = *(const float4*)(el4 + (size_t)s * 4);
      d0 += __expf(leaky(e.x + erv.x) - m0);
      d1 += __expf(leaky(e.y + erv.y) - m1);
      d2 += __expf(leaky(e.z + erv.z) - m2);
      d3 += __expf(leaky(e.w + erv.w) - m3);
    }
    d0 = wsum_sh(d0); d1 = wsum_sh(d1); d2 = wsum_sh(d2); d3 = wsum_sh(d3);
    float i0 = d0 > 0.f ? 1.f / d0 : 0.f;
    float i1 = d1 > 0.f ? 1.f / d1 : 0.f;
    float i2 = d2 > 0.f ? 1.f / d2 : 0.f;
    float i3 = d3 > 0.f ? 1.f / d3 : 0.f;
    for (int k = s0; k < s1; ++k) {
      int s = csrc[k];
      float4 e = *(const float4*)(el4 + (size_t)s * 4);
      float w0 = __expf(leaky(e.x + erv.x) - m0) * i0;
      float w1 = __expf(leaky(e.y + erv.y) - m1) * i1;
      float w2 = __expf(leaky(e.z + erv.z) - m2) * i2;
      float w3 = __expf(leaky(e.w + erv.w) - m3) * i3;
      float wk = (hh == 0) ? w0 : (hh == 1) ? w1 : (hh == 2) ? w2 : w3;
      if (lane < 8) acc = fmaf(wk, feat4[(size_t)s * 8 + p], acc);
    }
    if (lane < 8) v = acc + res4[(size_t)node * 8 + lane] + b4[lane];
  }

  float pv = __shfl_xor(v, 1);
  float mx = fmaxf(v, pv);
  float ex = __expf(v - mx);
  float sm = ex + __shfl_xor(ex, 1);
  float pr = ex / sm;
  float t = pr + __shfl_xor(pr, 2);
  t += __shfl_xor(t, 4);
  if (lane < 2) out[(size_t)node * 2 + lane] = t * 0.25f;
}

extern "C" void kernel_launch(void* const* d_in, const int* in_sizes, int n_in,
                              void* d_out, int out_size, void* d_ws, size_t ws_size,
                              hipStream_t stream) {
  const float* x   = (const float*)d_in[0];
  const int* src   = (const int*)d_in[1];
  const int* dst   = (const int*)d_in[2];
  const float* W1  = (const float*)d_in[3];
  const float* al1 = (const float*)d_in[4];
  const float* ar1 = (const float*)d_in[5];
  const float* b1  = (const float*)d_in[6];
  const float* W2  = (const float*)d_in[7];
  const float* al2 = (const float*)d_in[8];
  const float* ar2 = (const float*)d_in[9];
  const float* b2  = (const float*)d_in[10];
  const float* W3  = (const float*)d_in[11];
  const float* al3 = (const float*)d_in[12];
  const float* ar3 = (const float*)d_in[13];
  const float* b3  = (const float*)d_in[14];
  const float* W4  = (const float*)d_in[15];
  const float* al4 = (const float*)d_in[16];
  const float* ar4 = (const float*)d_in[17];
  const float* b4  = (const float*)d_in[18];
  const float* rW4 = (const float*)d_in[19];
  float* out = (float*)d_out;

  const int n = in_sizes[0] / 128;  // 50000
  const int e = in_sizes[1];        // 800000

  char* ws = (char*)d_ws;
  auto alloc = [&](size_t bytes) -> char* {
    char* p = ws;
    ws += (bytes + 255) & ~(size_t)255;
    return p;
  };
  __hip_bfloat16* featb = (__hip_bfloat16*)alloc((size_t)n * 256 * 2);
  __hip_bfloat16* h1b   = (__hip_bfloat16*)alloc((size_t)n * 256 * 2);
  __hip_bfloat16* h2b   = (__hip_bfloat16*)alloc((size_t)n * 256 * 2);
  __hip_bfloat16* h3b   = (__hip_bfloat16*)alloc((size_t)n * 256 * 2);
  __hip_bfloat16* W1b   = (__hip_bfloat16*)alloc((size_t)256 * 128 * 2);
  __hip_bfloat16* W2b   = (__hip_bfloat16*)alloc((size_t)256 * 256 * 2);
  __hip_bfloat16* W3b   = (__hip_bfloat16*)alloc((size_t)256 * 256 * 2);
  __hip_bfloat16* Wcatb = (__hip_bfloat16*)alloc((size_t)16 * 256 * 2);
  float* el    = (float*)alloc((size_t)n * 4 * 4);
  float* er    = (float*)alloc((size_t)n * 4 * 4);
  float* feat4 = (float*)alloc((size_t)n * 8 * 4);
  float* res4  = (float*)alloc((size_t)n * 8 * 4);
  float* el4   = (float*)alloc((size_t)n * 4 * 4);
  float* er4   = (float*)alloc((size_t)n * 4 * 4);
  int* deg     = (int*)alloc((size_t)n * 4);
  int* rowp    = (int*)alloc((size_t)(n + 1) * 4);
  int* csrc    = (int*)alloc((size_t)e * 4);
  int* slot    = (int*)alloc((size_t)e * 4);
  int nb_scan  = (n + 1023) / 1024;
  int* bsum    = (int*)alloc((size_t)(nb_scan + 1) * 4);

  (void)hipMemsetAsync(deg, 0, (size_t)n * 4, stream);

  cvthist_k<<<(e + 255) / 256, 256, 0, stream>>>(W1, W2, W3, W4, rW4, W1b, W2b, W3b,
                                                 Wcatb, dst, deg, slot, e);
  scan1_k<<<nb_scan, 1024, 0, stream>>>(deg, rowp, bsum, n);
  scan23_k<<<(n + 256) / 256, 256, 0, stream>>>(bsum, rowp, n, nb_scan);

  int nbx = (n + 127) / 128;
  int ggx = ((2 * nbx + 15) / 16) * 16;
  int nsc = (e + 255) / 256;
  int nb4 = (n + 3) / 4;

  // layer 1 (f32 x read directly) + fused scatter tail blocks
  gemm1f_mfma<<<ggx + nsc, 256, 0, stream>>>(x, W1b, featb, al1, ar1, el, er, n, nbx,
                                             ggx, src, dst, rowp, slot, csrc, e);
  agg64_k<0><<<nb4, 256, 0, stream>>>(featb, el, er, rowp, csrc, nullptr, b1, h1b, n);
  // layer 2
  gemm_mfma<256><<<ggx, 256, 0, stream>>>(h1b, W2b, featb, al2, ar2, el, er, n, nbx);
  agg64_k<1><<<nb4, 256, 0, stream>>>(featb, el, er, rowp, csrc, h1b, b2, h2b, n);
  // layer 3
  gemm_mfma<256><<<ggx, 256, 0, stream>>>(h2b, W3b, featb, al3, ar3, el, er, n, nbx);
  agg64_k<1><<<nb4, 256, 0, stream>>>(featb, el, er, rowp, csrc, h2b, b3, h3b, n);
  // layer 4
  int n16 = (n + 15) / 16;
  l4mfma_k<<<(n16 + 3) / 4, 256, 0, stream>>>(h3b, Wcatb, al4, ar4, feat4, res4, el4, er4, n);
  agg4_k<<<nb4, 256, 0, stream>>>(feat4, el4, er4, rowp, csrc, res4, b4, out, n);
}